// Round 10
// baseline (432.726 us; speedup 1.0000x reference)
//
#include <hip/hip_runtime.h>
#include <hip/hip_bf16.h>

#define Tt 2048
#define Dd 2048
#define Ff 512
#define Ee 16
#define NE 17                    // 16 routed experts + 1 shared
#define MAXROWS 12288            // 80 routed tiles*128 + 16 shared tiles*128
#define MAXTILES 96

typedef __attribute__((ext_vector_type(8))) short short8;
typedef __attribute__((ext_vector_type(8))) unsigned short ushort8v;
typedef __attribute__((ext_vector_type(4))) float floatx4;

#define AS1 __attribute__((address_space(1)))
#define AS3 __attribute__((address_space(3)))

__device__ __forceinline__ unsigned short f2bf(float f) {
    union { float f; unsigned u; } v; v.f = f;
    unsigned r = v.u + 0x7FFFu + ((v.u >> 16) & 1u);   // RNE
    return (unsigned short)(r >> 16);
}
__device__ __forceinline__ float bf2f(unsigned short h) {
    union { unsigned u; float f; } v; v.u = ((unsigned)h) << 16;
    return v.f;
}

__device__ __forceinline__ void gld16(const unsigned short* g, unsigned short* l) {
    __builtin_amdgcn_global_load_lds((const AS1 void*)g, (AS3 void*)l, 16, 0, 0);
}

// LDS tile swizzle (rows of 32 shorts = 4 sub-blocks of 8 shorts = 16B):
//   data (row, sub q) lives at sub q ^ ((row>>1)&3).
// LDS staging stays LINEAR for global_load_lds; the SOURCE address is pre-permuted
// (m173 pattern). Stage thread tid (dest row tid>>2, dest sub tid&3) reads source sub:
//   swz8 = ((tid&3) ^ ((tid>>3)&3)) * 8
// Read of (row, k-sub quad): row bits1-2 == lr bits1-2 for all fragment rows, so
//   koff = (quad ^ ((lr>>1)&3)) * 8
// [round 9 verified: SQ_LDS_BANK_CONFLICT 5.64M -> 0]

// ---------------- split-cast x -> bf16 hi + bf16 lo ----------------
__global__ void splitcast_x(const float* __restrict__ x, unsigned short* __restrict__ xh,
                            unsigned short* __restrict__ xl) {
    int i = (blockIdx.x * 256 + threadIdx.x) * 8;
    float v[8];
    *(floatx4*)&v[0] = *(const floatx4*)(x + i);
    *(floatx4*)&v[4] = *(const floatx4*)(x + i + 4);
    ushort8v h, l;
#pragma unroll
    for (int j = 0; j < 8; j++) {
        unsigned short hb = f2bf(v[j]);
        h[j] = hb;
        l[j] = f2bf(v[j] - bf2f(hb));
    }
    *(ushort8v*)(xh + i) = h;
    *(ushort8v*)(xl + i) = l;
}

// ---------------- split gate weights into gB[2][32][2048] (hi,lo), rows 17..31 zero ----------------
__global__ void splitg_kernel(const float* __restrict__ gw, const float* __restrict__ sgw,
                              unsigned short* __restrict__ gB) {
    int z = blockIdx.x;                // 0..31
    int i = threadIdx.x * 8;
    ushort8v h = {0,0,0,0,0,0,0,0}, l = {0,0,0,0,0,0,0,0};
    if (z < NE) {
        const float* src = (z < Ee) ? (gw + (size_t)z * Dd) : sgw;
        float v[8];
        *(floatx4*)&v[0] = *(const floatx4*)(src + i);
        *(floatx4*)&v[4] = *(const floatx4*)(src + i + 4);
#pragma unroll
        for (int j = 0; j < 8; j++) {
            unsigned short hb = f2bf(v[j]);
            h[j] = hb;
            l[j] = f2bf(v[j] - bf2f(hb));
        }
    }
    *(ushort8v*)(gB + (size_t)z * Dd + i) = h;
    *(ushort8v*)(gB + 32 * Dd + (size_t)z * Dd + i) = l;
}

// ---------------- pre-cast Wg/Wu (+shared) -> bf16 tile-image (swizzle baked) ----------------
// WguP[e][n0b][kb][p][2048]: 64x32 (n x k) tile, p=0 gate / p=1 up.
__global__ __launch_bounds__(256) void cast_wgu_kernel(
    const float* __restrict__ Wg, const float* __restrict__ sWg,
    const float* __restrict__ Wu, const float* __restrict__ sWu,
    unsigned short* __restrict__ WguP)
{
    __shared__ unsigned short sT[64 * 32];     // [n][k-swizzled]
    const int kb  = blockIdx.x;                // 0..63
    const int n0b = blockIdx.y;                // 0..7
    const int z   = blockIdx.z;                // 0..33
    const int e = z >> 1, p = z & 1;
    const float* src = p ? ((e < Ee) ? (Wu + (size_t)e * Dd * Ff) : sWu)
                         : ((e < Ee) ? (Wg + (size_t)e * Dd * Ff) : sWg);
    const int t = threadIdx.x;
    const int krow = t >> 3;                   // 0..31
    const int nn = (t & 7) * 8;                // 0..56
    const float* s = src + (size_t)(kb * 32 + krow) * Ff + n0b * 64 + nn;
    float v[8];
    *(floatx4*)&v[0] = *(const floatx4*)(s);
    *(floatx4*)&v[4] = *(const floatx4*)(s + 4);
#pragma unroll
    for (int w = 0; w < 8; w++) {
        const int nrow = nn + w;
        const int ksw = (((krow >> 3) ^ ((nrow >> 1) & 3)) * 8) + (krow & 7);
        sT[nrow * 32 + ksw] = f2bf(v[w]);
    }
    __syncthreads();
    unsigned short* dst = WguP + ((((size_t)(e * 8 + n0b) * 64 + kb) * 2 + p) * 2048);
    *(ushort8v*)(dst + t * 8) = *(const ushort8v*)&sT[t * 8];
}

// ---------------- pre-cast Wd (+shared) -> bf16 tile-image (swizzle baked) ----------------
// WdP[e][n0b][kb][4096]: 128x32 (n x k) tile.
__global__ __launch_bounds__(256) void cast_wd_kernel(
    const float* __restrict__ Wd, const float* __restrict__ sWd,
    unsigned short* __restrict__ WdP)
{
    __shared__ unsigned short sT[128 * 32];    // [n][k-swizzled]
    const int kb  = blockIdx.x;                // 0..15
    const int n0b = blockIdx.y;                // 0..15
    const int e   = blockIdx.z;                // 0..16
    const float* src = (e < Ee) ? (Wd + (size_t)e * Ff * Dd) : sWd;
    const int t = threadIdx.x;
    const int krow = t >> 3;                   // 0..31
    const int nn = (t & 7) * 16;               // 0..112
    const float* s = src + (size_t)(kb * 32 + krow) * Dd + n0b * 128 + nn;
    float v[16];
#pragma unroll
    for (int q = 0; q < 4; q++) *(floatx4*)&v[q * 4] = *(const floatx4*)(s + q * 4);
#pragma unroll
    for (int w = 0; w < 16; w++) {
        const int nrow = nn + w;
        const int ksw = (((krow >> 3) ^ ((nrow >> 1) & 3)) * 8) + (krow & 7);
        sT[nrow * 32 + ksw] = f2bf(v[w]);
    }
    __syncthreads();
    unsigned short* dst = WdP + (((size_t)(e * 16 + n0b) * 16 + kb) * 4096);
    *(ushort8v*)(dst + t * 8) = *(const ushort8v*)&sT[t * 8];
    *(ushort8v*)(dst + 2048 + t * 8) = *(const ushort8v*)&sT[2048 + t * 8];
}

// ---------------- logits GEMM (unchanged) ----------------
__global__ __launch_bounds__(256) void logits_kernel(
    const unsigned short* __restrict__ xh, const unsigned short* __restrict__ xl,
    const unsigned short* __restrict__ gB, float* __restrict__ part) {
    __shared__ unsigned short sAh[128 * 32];
    __shared__ unsigned short sAl[128 * 32];
    __shared__ unsigned short sB[2048];     // [0..1023] hi 32x32, [1024..2047] lo 32x32
    const int m0 = blockIdx.x * 128;
    const int kb = blockIdx.y;
    const int k00 = kb * 256;
    const int tid = threadIdx.x;
    const int lane = tid & 63, wv = tid >> 6;
    const int lr = lane & 15, quad = lane >> 4;

    const int l0 = tid * 8;
    const int r0 = l0 >> 5, c0 = l0 & 31;
    const int l1 = l0 + 2048;
    const int r1 = r0 + 64;
    const int br = (tid >> 2) & 31, bc = (tid & 3) * 8;
    const unsigned short* bsrc = gB + ((tid >= 128) ? 32 * Dd : 0) + (size_t)br * Dd + bc;

    floatx4 acc[2][2];
#pragma unroll
    for (int i = 0; i < 2; i++)
#pragma unroll
        for (int j = 0; j < 2; j++) acc[i][j] = (floatx4){0.f, 0.f, 0.f, 0.f};

    for (int kk = 0; kk < 256; kk += 32) {
        __syncthreads();
        gld16(xh + (size_t)(m0 + r0) * Dd + k00 + kk + c0, &sAh[l0]);
        gld16(xh + (size_t)(m0 + r1) * Dd + k00 + kk + c0, &sAh[l1]);
        gld16(xl + (size_t)(m0 + r0) * Dd + k00 + kk + c0, &sAl[l0]);
        gld16(xl + (size_t)(m0 + r1) * Dd + k00 + kk + c0, &sAl[l1]);
        gld16(bsrc + k00 + kk, &sB[l0 & 2047]);
        __syncthreads();
#pragma unroll
        for (int mi = 0; mi < 2; mi++) {
            const int ar = wv * 32 + mi * 16 + lr;
            short8 ah = *(const short8*)&sAh[ar * 32 + quad * 8];
            short8 al = *(const short8*)&sAl[ar * 32 + quad * 8];
#pragma unroll
            for (int nj = 0; nj < 2; nj++) {
                short8 bh = *(const short8*)&sB[(nj * 16 + lr) * 32 + quad * 8];
                short8 bl = *(const short8*)&sB[1024 + (nj * 16 + lr) * 32 + quad * 8];
                acc[mi][nj] = __builtin_amdgcn_mfma_f32_16x16x32_bf16(ah, bh, acc[mi][nj], 0, 0, 0);
                acc[mi][nj] = __builtin_amdgcn_mfma_f32_16x16x32_bf16(ah, bl, acc[mi][nj], 0, 0, 0);
                acc[mi][nj] = __builtin_amdgcn_mfma_f32_16x16x32_bf16(al, bh, acc[mi][nj], 0, 0, 0);
            }
        }
    }
#pragma unroll
    for (int mi = 0; mi < 2; mi++)
#pragma unroll
        for (int r = 0; r < 4; r++) {
            const int t = m0 + wv * 32 + mi * 16 + quad * 4 + r;
#pragma unroll
            for (int nj = 0; nj < 2; nj++)
                part[((size_t)kb * Tt + t) * 32 + nj * 16 + lr] = acc[mi][nj][r];
        }
}

// ---------------- topk: reduce split-K partials, softmax, top4, shared gate ----------------
__global__ void topk_kernel(const float* __restrict__ part, float* __restrict__ comb,
                            int* __restrict__ selids, int* __restrict__ counts) {
    const int t = blockIdx.x * 64 + threadIdx.x;
    float lg[20];
#pragma unroll
    for (int j = 0; j < 20; j++) lg[j] = 0.f;
#pragma unroll
    for (int kb = 0; kb < 8; kb++) {
        const float* p = part + ((size_t)kb * Tt + t) * 32;
#pragma unroll
        for (int q = 0; q < 5; q++) {
            floatx4 a = *(const floatx4*)(p + q * 4);
            lg[q * 4 + 0] += a.x; lg[q * 4 + 1] += a.y;
            lg[q * 4 + 2] += a.z; lg[q * 4 + 3] += a.w;
        }
    }
    float mx = lg[0];
    for (int e = 1; e < Ee; e++) mx = fmaxf(mx, lg[e]);
    float p[Ee]; float sum = 0.f;
    for (int e = 0; e < Ee; e++) { p[e] = __expf(lg[e] - mx); sum += p[e]; }
    float inv = 1.f / sum;
    for (int e = 0; e < Ee; e++) p[e] *= inv;
    bool sel[Ee];
    for (int e = 0; e < Ee; e++) sel[e] = false;
    int ids[4];
    float ssum = 0.f;
    for (int k = 0; k < 4; k++) {
        int bi = 0; float bv = -1.f;
        for (int e = 0; e < Ee; e++)
            if (!sel[e] && p[e] > bv) { bv = p[e]; bi = e; }
        sel[bi] = true; ids[k] = bi; ssum += bv;
    }
    float rinv = 1.f / ssum;
    for (int e = 0; e < Ee; e++) comb[t * NE + e] = sel[e] ? p[e] * rinv : 0.f;
    comb[t * NE + Ee] = 1.f / (1.f + __expf(-lg[16]));
#pragma unroll
    for (int k = 0; k < 4; k++) {
        selids[t * 4 + k] = ids[k];
        atomicAdd(&counts[ids[k]], 1);
    }
}

// ---------------- offsets: tile-padded exclusive scan + block table ----------------
__global__ void offsets_kernel(const int* __restrict__ counts, int* __restrict__ off,
                               int* __restrict__ cursor, int* __restrict__ blocktab,
                               int* __restrict__ meta) {
    int acc = 0, nt = 0;
    for (int e = 0; e < NE; e++) {
        int c = (e < Ee) ? counts[e] : Tt;
        off[e] = acc;
        if (e < Ee) cursor[e] = 0;
        int tiles = (c + 127) >> 7;
        for (int tl = 0; tl < tiles; tl++) blocktab[nt++] = (e << 20) | (acc + tl * 128);
        acc += tiles << 7;
    }
    meta[0] = nt;
}

// ---------------- scatter: rowmap (pos -> token) + tokpos (token -> its 5 positions) ----------------
__global__ void scatter_kernel(const int* __restrict__ selids, const int* __restrict__ off,
                               int* __restrict__ cursor, int* __restrict__ rowmap,
                               int* __restrict__ tokpos) {
    int t = blockIdx.x * 256 + threadIdx.x;
    if (t >= Tt) return;
#pragma unroll
    for (int k = 0; k < 4; k++) {
        int e = selids[t * 4 + k];
        int r = atomicAdd(&cursor[e], 1);
        int pos = off[e] + r;
        rowmap[pos] = t;
        tokpos[t * 8 + k] = pos;
    }
    int sp = off[Ee] + t;
    rowmap[sp] = t;            // shared expert: identity
    tokpos[t * 8 + 4] = sp;
}

// ---------------- GEMM1: Hp[pos][f] = comb * silu(x@Wg_e) * (x@Wu_e) ----------------
// 64x64 m-split tiles (was 128x64): grid 1344 blocks -> ~5.25/CU for TLP-based
// latency hiding of the 2-phase barrier drain (round-9: occupancy 24%, grid-limited
// at 2.6 blocks/CU was the gemm1 ceiling). Sibling blocks y=2t,2t+1 take halves of
// blocktab[t] and share B-tiles (L2 hits). LDS 24KB/block (6 resident possible).
// Same 2-phase __syncthreads template + swizzle as round 9 (verified).
__global__ __launch_bounds__(256, 5) void gemm1_pre_kernel(
    const unsigned short* __restrict__ xb,
    const unsigned short* __restrict__ WguP,
    const float* __restrict__ comb,
    const int* __restrict__ rowmap,
    const int* __restrict__ blocktab,
    const int* __restrict__ meta,
    unsigned short* __restrict__ Hp)
{
    const int y = blockIdx.y;
    if ((int)(y >> 1) >= meta[0]) return;
    __shared__ unsigned short sAb[2][2048];   // A tiles (64x32)
    __shared__ unsigned short sGb[2][2048];   // gate B tiles (64x32)
    __shared__ unsigned short sUb[2][2048];   // up B tiles (64x32)
    const int info = blocktab[y >> 1];
    const int e  = info >> 20;
    const int m0 = (info & 0xFFFFF) + (y & 1) * 64;
    const int n0b = blockIdx.x;
    const int n0 = n0b * 64;
    const int tid = threadIdx.x;
    const int lane = tid & 63, wv = tid >> 6;
    const int wm = (wv >> 1) * 32, wn = (wv & 1) * 32;
    const int lr = lane & 15, quad = lane >> 4;
    const int swz8 = ((tid & 3) ^ ((tid >> 3) & 3)) * 8;
    const int koff = (quad ^ ((lr >> 1) & 3)) * 8;

    const unsigned short* wbase = WguP + (size_t)(e * 8 + n0b) * 64 * 4096;

    const int l0 = tid * 8;
    const int r0 = l0 >> 5;                   // 0..63
    const int tk0 = rowmap[m0 + r0];
    const unsigned short* a0 = xb + (size_t)(tk0 < 0 ? 0 : tk0) * Dd + swz8;

#define G1STAGE(B, KB) do { \
        const unsigned short* wsrc_ = wbase + (size_t)(KB) * 4096; \
        gld16(a0 + (KB) * 32, &sAb[B][l0]); \
        gld16(wsrc_ + l0, &sGb[B][l0]); \
        gld16(wsrc_ + 2048 + l0, &sUb[B][l0]); \
    } while (0)

    floatx4 accg[2][2], accu[2][2];
#pragma unroll
    for (int i = 0; i < 2; i++)
#pragma unroll
        for (int j = 0; j < 2; j++) {
            accg[i][j] = (floatx4){0.f, 0.f, 0.f, 0.f};
            accu[i][j] = (floatx4){0.f, 0.f, 0.f, 0.f};
        }

    G1STAGE(0, 0);
    __syncthreads();                         // tile 0 resident
    for (int kb = 0; kb < 64; kb++) {
        const int cur = kb & 1;
        if (kb < 63) G1STAGE(cur ^ 1, kb + 1);   // in flight during MFMA below
        short8 af[2];
#pragma unroll
        for (int i = 0; i < 2; i++)
            af[i] = *(const short8*)&sAb[cur][(wm + i * 16 + lr) * 32 + koff];
#pragma unroll
        for (int j = 0; j < 2; j++) {
            short8 bg = *(const short8*)&sGb[cur][(wn + j * 16 + lr) * 32 + koff];
            short8 bu = *(const short8*)&sUb[cur][(wn + j * 16 + lr) * 32 + koff];
#pragma unroll
            for (int i = 0; i < 2; i++) {
                accg[i][j] = __builtin_amdgcn_mfma_f32_16x16x32_bf16(af[i], bg, accg[i][j], 0, 0, 0);
                accu[i][j] = __builtin_amdgcn_mfma_f32_16x16x32_bf16(af[i], bu, accu[i][j], 0, 0, 0);
            }
        }
        __syncthreads();                     // drains stage(kb+1); guards buffer reuse
    }
#undef G1STAGE
#pragma unroll
    for (int i = 0; i < 2; i++) {
#pragma unroll
        for (int r = 0; r < 4; r++) {
            const int pos = m0 + wm + i * 16 + quad * 4 + r;
            const int tok = rowmap[pos];
            const float wc = (tok >= 0) ? comb[tok * NE + e] : 0.f;
#pragma unroll
            for (int j = 0; j < 2; j++) {
                const float g = accg[i][j][r];
                const float u = accu[i][j][r];
                const float h = (g / (1.f + __expf(-g))) * u * wc;
                Hp[(size_t)pos * Ff + (n0 + wn + j * 16 + lr)] = f2bf(h);
            }
        }
    }
}

// ---------------- GEMM2: Op[pos] = Hp[pos] @ Wd_e (pre-cast bf16 Wd, packed bf16 out) ----------------
__global__ __launch_bounds__(256, 4) void gemm2_pre_kernel(
    const unsigned short* __restrict__ Hp,
    const unsigned short* __restrict__ WdP,
    const int* __restrict__ blocktab,
    const int* __restrict__ meta,
    unsigned short* __restrict__ Op)          // [MAXROWS][D] bf16 packed
{
    if ((int)blockIdx.y >= meta[0]) return;
    __shared__ unsigned short sA2[2][4096];
    __shared__ unsigned short sB2[2][4096];
    const int info = blocktab[blockIdx.y];
    const int e  = info >> 20;
    const int m0 = info & 0xFFFFF;
    const int n0b = blockIdx.x;
    const int n0 = n0b * 128;
    const int tid = threadIdx.x;
    const int lane = tid & 63, wv = tid >> 6;
    const int wm = (wv >> 1) * 64, wn = (wv & 1) * 64;
    const int lr = lane & 15, quad = lane >> 4;
    const int swz8 = ((tid & 3) ^ ((tid >> 3) & 3)) * 8;
    const int koff = (quad ^ ((lr >> 1) & 3)) * 8;

    const unsigned short* Ab = Hp + (size_t)m0 * Ff;
    const unsigned short* wbase = WdP + (size_t)(e * 16 + n0b) * 16 * 4096;

    const int l0 = tid * 8;
    const int r0 = l0 >> 5;
    const int r1 = r0 + 64;
    const unsigned short* aA0 = Ab + (size_t)r0 * Ff + swz8;
    const unsigned short* aA1 = Ab + (size_t)r1 * Ff + swz8;

#define G2STAGE(B, KB) do { \
        const unsigned short* wsrc_ = wbase + (size_t)(KB) * 4096; \
        gld16(aA0 + (KB) * 32, &sA2[B][l0]); \
        gld16(aA1 + (KB) * 32, &sA2[B][l0 + 2048]); \
        gld16(wsrc_ + l0, &sB2[B][l0]); \
        gld16(wsrc_ + 2048 + l0, &sB2[B][l0 + 2048]); \
    } while (0)

    floatx4 acc[4][4];
#pragma unroll
    for (int i = 0; i < 4; i++)
#pragma unroll
        for (int j = 0; j < 4; j++) acc[i][j] = (floatx4){0.f, 0.f, 0.f, 0.f};

    G2STAGE(0, 0);
    __syncthreads();
    for (int kb = 0; kb < 16; kb++) {
        const int cur = kb & 1;
        if (kb < 15) G2STAGE(cur ^ 1, kb + 1);
        short8 af[4];
#pragma unroll
        for (int i = 0; i < 4; i++)
            af[i] = *(const short8*)&sA2[cur][(wm + i * 16 + lr) * 32 + koff];
#pragma unroll
        for (int j = 0; j < 4; j++) {
            short8 bf = *(const short8*)&sB2[cur][(wn + j * 16 + lr) * 32 + koff];
#pragma unroll
            for (int i = 0; i < 4; i++)
                acc[i][j] = __builtin_amdgcn_mfma_f32_16x16x32_bf16(af[i], bf, acc[i][j], 0, 0, 0);
        }
        __syncthreads();                     // drains stage(kb+1); guards buffer reuse
    }
#undef G2STAGE
    // epilogue: per-wave 64x64 bf16 tile staged through LDS, coalesced ushort8 stores
    // (loop's final __syncthreads guarantees all K-loop LDS reads are done)
    unsigned short* sOut = &sA2[0][0] + wv * 2048;  // 4 KB per wave
#pragma unroll
    for (int h = 0; h < 2; h++) {
#pragma unroll
        for (int ii = 0; ii < 2; ii++) {
            const int i = h * 2 + ii;
#pragma unroll
            for (int r = 0; r < 4; r++) {
                const int lrow = ii * 16 + quad * 4 + r;
#pragma unroll
                for (int j = 0; j < 4; j++)
                    sOut[lrow * 64 + j * 16 + lr] = f2bf(acc[i][j][r]);
            }
        }
        __syncthreads();
        const int prow0 = m0 + wm + h * 32;
#pragma unroll
        for (int it = 0; it < 4; it++) {
            const int idx = it * 512 + lane * 8;
            const int row = idx >> 6, col = idx & 63;
            ushort8v vv = *(const ushort8v*)&sOut[row * 64 + col];
            *(ushort8v*)&Op[(size_t)(prow0 + row) * Dd + n0 + wn + col] = vv;
        }
        __syncthreads();
    }
}

// ---------------- reduce: out[t] = sum of the token's 5 packed Op rows ----------------
__global__ __launch_bounds__(256) void reduce_kernel(
    const unsigned short* __restrict__ Op, const int* __restrict__ tokpos,
    float* __restrict__ out)
{
    const int t = blockIdx.x;
    const int c = threadIdx.x * 8;
    int ps[5];
#pragma unroll
    for (int k = 0; k < 5; k++) ps[k] = tokpos[t * 8 + k];
    float s[8];
#pragma unroll
    for (int j = 0; j < 8; j++) s[j] = 0.f;
#pragma unroll
    for (int k = 0; k < 5; k++) {
        ushort8v v = *(const ushort8v*)&Op[(size_t)ps[k] * Dd + c];
#pragma unroll
        for (int j = 0; j < 8; j++) s[j] += bf2f(v[j]);
    }
    *(floatx4*)(out + (size_t)t * Dd + c) = *(floatx4*)&s[0];
    *(floatx4*)(out + (size_t)t * Dd + c + 4) = *(floatx4*)&s[4];
}

extern "C" void kernel_launch(void* const* d_in, const int* in_sizes, int n_in,
                              void* d_out, int out_size, void* d_ws, size_t ws_size,
                              hipStream_t stream) {
    const float* x   = (const float*)d_in[0];
    const float* gw  = (const float*)d_in[1];
    const float* Wg  = (const float*)d_in[2];
    const float* Wu  = (const float*)d_in[3];
    const float* Wd  = (const float*)d_in[4];
    const float* sWg = (const float*)d_in[5];
    const float* sWu = (const float*)d_in[6];
    const float* sWd = (const float*)d_in[7];
    const float* sgw = (const float*)d_in[8];
    float* out = (float*)d_out;

    // workspace layout: 139.0 MB. WguP (dead after gemm1) overlays Op (live from gemm2).
    char* ws = (char*)d_ws;
    unsigned short* xb   = (unsigned short*)(ws);                //  8,388,608
    unsigned short* xl   = (unsigned short*)(ws + 8388608);      //  8,388,608
    unsigned short* Hp   = (unsigned short*)(ws + 16777216);     // 12,582,912
    float* part    = (float*)(ws + 29360128);                    //  2,097,152
    unsigned short* gB   = (unsigned short*)(ws + 31457280);     //    262,144
    float* comb    = (float*)(ws + 31719424);                    //    139,264
    int* selids    = (int*)(ws + 31858688);                      //     32,768
    int* counts    = (int*)(ws + 31891456);                      //         64
    int* off       = (int*)(ws + 31891520);                      //        128
    int* cursor    = (int*)(ws + 31891648);                      //         64
    int* meta      = (int*)(ws + 31891712);                      //         64
    int* blocktab  = (int*)(ws + 31891776);                      //        512
    int* rowmap    = (int*)(ws + 31892288);                      //     49,152
    int* tokpos    = (int*)(ws + 31941440);                      //     65,536
    unsigned short* WdP  = (unsigned short*)(ws + 32006976);     // 35,651,584
    unsigned short* WguP = (unsigned short*)(ws + 67658560);     // 71,303,168 (union w/ Op)
    unsigned short* Op   = (unsigned short*)(ws + 67658560);     // 50,331,648 (union w/ WguP)

    splitcast_x<<<Tt * Dd / 2048, 256, 0, stream>>>(x, xb, xl);
    splitg_kernel<<<32, 256, 0, stream>>>(gw, sgw, gB);
    cast_wgu_kernel<<<dim3(64, 8, 34), 256, 0, stream>>>(Wg, sWg, Wu, sWu, WguP);
    cast_wd_kernel<<<dim3(16, 16, 17), 256, 0, stream>>>(Wd, sWd, WdP);
    logits_kernel<<<dim3(Tt / 128, 8), 256, 0, stream>>>(xb, xl, gB, part);
    hipMemsetAsync(counts, 0, 64, stream);
    topk_kernel<<<Tt / 64, 64, 0, stream>>>(part, comb, selids, counts);
    offsets_kernel<<<1, 1, 0, stream>>>(counts, off, cursor, blocktab, meta);
    hipMemsetAsync(rowmap, 0xFF, MAXROWS * sizeof(int), stream);
    scatter_kernel<<<8, 256, 0, stream>>>(selids, off, cursor, rowmap, tokpos);
    gemm1_pre_kernel<<<dim3(Ff / 64, MAXTILES * 2), 256, 0, stream>>>(
        xb, WguP, comb, rowmap, blocktab, meta, Hp);
    gemm2_pre_kernel<<<dim3(Dd / 128, MAXTILES), 256, 0, stream>>>(
        Hp, WdP, blocktab, meta, Op);
    reduce_kernel<<<Tt, 256, 0, stream>>>(Op, tokpos, out);
}

// Round 11
// 408.860 us; speedup vs baseline: 1.0584x; 1.0584x over previous
//
#include <hip/hip_runtime.h>
#include <hip/hip_bf16.h>

#define Tt 2048
#define Dd 2048
#define Ff 512
#define Ee 16
#define NE 17                    // 16 routed experts + 1 shared
#define MAXROWS 12288            // 80 routed tiles*128 + 16 shared tiles*128
#define MAXTILES 96

typedef __attribute__((ext_vector_type(8))) short short8;
typedef __attribute__((ext_vector_type(8))) unsigned short ushort8v;
typedef __attribute__((ext_vector_type(4))) float floatx4;

#define AS1 __attribute__((address_space(1)))
#define AS3 __attribute__((address_space(3)))

__device__ __forceinline__ unsigned short f2bf(float f) {
    union { float f; unsigned u; } v; v.f = f;
    unsigned r = v.u + 0x7FFFu + ((v.u >> 16) & 1u);   // RNE
    return (unsigned short)(r >> 16);
}
__device__ __forceinline__ float bf2f(unsigned short h) {
    union { unsigned u; float f; } v; v.u = ((unsigned)h) << 16;
    return v.f;
}

__device__ __forceinline__ void gld16(const unsigned short* g, unsigned short* l) {
    __builtin_amdgcn_global_load_lds((const AS1 void*)g, (AS3 void*)l, 16, 0, 0);
}

// LDS tile swizzle (rows of 32 shorts = 4 sub-blocks of 8 shorts = 16B):
//   data (row, sub q) lives at sub q ^ ((row>>1)&3).
// Staging stays LINEAR for global_load_lds; the SOURCE address is pre-permuted.
//   swz8 = ((tid&3) ^ ((tid>>3)&3)) * 8      (stage side)
//   koff = (quad ^ ((lr>>1)&3)) * 8          (read side)
// [round 9 verified: SQ_LDS_BANK_CONFLICT 5.64M -> 0]

// ---------------- prep: fused splitcast_x | splitg | cast_wgu | cast_wd |
//                  rowmap fill | counts zero  (dispatch-count reduction 15->8) ----------
// block ranges:
//   [0,2048)        splitcast_x
//   [2048,2080)     splitg (32)
//   [2080,19488)    cast_wgu (64x8x34)
//   [19488,23840)   cast_wd (16x16x17)
//   [23840,23888)   rowmap = -1 (48*256 = 12288)
//   [23888]         counts = 0
#define PREP_BLOCKS 23889
__global__ __launch_bounds__(256) void prep_kernel(
    const float* __restrict__ x,
    const float* __restrict__ gw,  const float* __restrict__ sgw,
    const float* __restrict__ Wg,  const float* __restrict__ sWg,
    const float* __restrict__ Wu,  const float* __restrict__ sWu,
    const float* __restrict__ Wd,  const float* __restrict__ sWd,
    unsigned short* __restrict__ xh, unsigned short* __restrict__ xl,
    unsigned short* __restrict__ gB,
    unsigned short* __restrict__ WguP, unsigned short* __restrict__ WdP,
    int* __restrict__ counts, int* __restrict__ rowmap)
{
    __shared__ unsigned short sT[128 * 32];    // 8 KB; used by both cast paths
    const int b = blockIdx.x;
    const int t = threadIdx.x;

    if (b < 2048) {
        // ---- splitcast x -> bf16 hi + lo ----
        int i = (b * 256 + t) * 8;
        float v[8];
        *(floatx4*)&v[0] = *(const floatx4*)(x + i);
        *(floatx4*)&v[4] = *(const floatx4*)(x + i + 4);
        ushort8v h, l;
#pragma unroll
        for (int j = 0; j < 8; j++) {
            unsigned short hb = f2bf(v[j]);
            h[j] = hb;
            l[j] = f2bf(v[j] - bf2f(hb));
        }
        *(ushort8v*)(xh + i) = h;
        *(ushort8v*)(xl + i) = l;
    } else if (b < 2080) {
        // ---- split gate weights -> gB[2][32][2048], rows 17..31 zero ----
        int z = b - 2048;
        int i = t * 8;
        ushort8v h = {0,0,0,0,0,0,0,0}, l = {0,0,0,0,0,0,0,0};
        if (z < NE) {
            const float* src = (z < Ee) ? (gw + (size_t)z * Dd) : sgw;
            float v[8];
            *(floatx4*)&v[0] = *(const floatx4*)(src + i);
            *(floatx4*)&v[4] = *(const floatx4*)(src + i + 4);
#pragma unroll
            for (int j = 0; j < 8; j++) {
                unsigned short hb = f2bf(v[j]);
                h[j] = hb;
                l[j] = f2bf(v[j] - bf2f(hb));
            }
        }
        *(ushort8v*)(gB + (size_t)z * Dd + i) = h;
        *(ushort8v*)(gB + 32 * Dd + (size_t)z * Dd + i) = l;
    } else if (b < 19488) {
        // ---- cast Wg/Wu -> WguP tile images (swizzle baked) ----
        const int idx = b - 2080;
        const int kb  = idx & 63;
        const int n0b = (idx >> 6) & 7;
        const int z   = idx >> 9;              // 0..33
        const int e = z >> 1, p = z & 1;
        const float* src = p ? ((e < Ee) ? (Wu + (size_t)e * Dd * Ff) : sWu)
                             : ((e < Ee) ? (Wg + (size_t)e * Dd * Ff) : sWg);
        const int krow = t >> 3;               // 0..31
        const int nn = (t & 7) * 8;            // 0..56
        const float* s = src + (size_t)(kb * 32 + krow) * Ff + n0b * 64 + nn;
        float v[8];
        *(floatx4*)&v[0] = *(const floatx4*)(s);
        *(floatx4*)&v[4] = *(const floatx4*)(s + 4);
#pragma unroll
        for (int w = 0; w < 8; w++) {
            const int nrow = nn + w;
            const int ksw = (((krow >> 3) ^ ((nrow >> 1) & 3)) * 8) + (krow & 7);
            sT[nrow * 32 + ksw] = f2bf(v[w]);
        }
        __syncthreads();
        unsigned short* dst = WguP + ((((size_t)(e * 8 + n0b) * 64 + kb) * 2 + p) * 2048);
        *(ushort8v*)(dst + t * 8) = *(const ushort8v*)&sT[t * 8];
    } else if (b < 23840) {
        // ---- cast Wd -> WdP tile images (swizzle baked) ----
        const int idx = b - 19488;
        const int kb  = idx & 15;
        const int n0b = (idx >> 4) & 15;
        const int e   = idx >> 8;              // 0..16
        const float* src = (e < Ee) ? (Wd + (size_t)e * Ff * Dd) : sWd;
        const int krow = t >> 3;               // 0..31
        const int nn = (t & 7) * 16;           // 0..112
        const float* s = src + (size_t)(kb * 32 + krow) * Dd + n0b * 128 + nn;
        float v[16];
#pragma unroll
        for (int q = 0; q < 4; q++) *(floatx4*)&v[q * 4] = *(const floatx4*)(s + q * 4);
#pragma unroll
        for (int w = 0; w < 16; w++) {
            const int nrow = nn + w;
            const int ksw = (((krow >> 3) ^ ((nrow >> 1) & 3)) * 8) + (krow & 7);
            sT[nrow * 32 + ksw] = f2bf(v[w]);
        }
        __syncthreads();
        unsigned short* dst = WdP + (((size_t)(e * 16 + n0b) * 16 + kb) * 4096);
        *(ushort8v*)(dst + t * 8) = *(const ushort8v*)&sT[t * 8];
        *(ushort8v*)(dst + 2048 + t * 8) = *(const ushort8v*)&sT[2048 + t * 8];
    } else if (b < 23888) {
        rowmap[(b - 23840) * 256 + t] = -1;
    } else {
        if (t < 16) counts[t] = 0;
    }
}

// ---------------- logits GEMM (unchanged) ----------------
__global__ __launch_bounds__(256) void logits_kernel(
    const unsigned short* __restrict__ xh, const unsigned short* __restrict__ xl,
    const unsigned short* __restrict__ gB, float* __restrict__ part) {
    __shared__ unsigned short sAh[128 * 32];
    __shared__ unsigned short sAl[128 * 32];
    __shared__ unsigned short sB[2048];     // [0..1023] hi 32x32, [1024..2047] lo 32x32
    const int m0 = blockIdx.x * 128;
    const int kb = blockIdx.y;
    const int k00 = kb * 256;
    const int tid = threadIdx.x;
    const int lane = tid & 63, wv = tid >> 6;
    const int lr = lane & 15, quad = lane >> 4;

    const int l0 = tid * 8;
    const int r0 = l0 >> 5, c0 = l0 & 31;
    const int l1 = l0 + 2048;
    const int r1 = r0 + 64;
    const int br = (tid >> 2) & 31, bc = (tid & 3) * 8;
    const unsigned short* bsrc = gB + ((tid >= 128) ? 32 * Dd : 0) + (size_t)br * Dd + bc;

    floatx4 acc[2][2];
#pragma unroll
    for (int i = 0; i < 2; i++)
#pragma unroll
        for (int j = 0; j < 2; j++) acc[i][j] = (floatx4){0.f, 0.f, 0.f, 0.f};

    for (int kk = 0; kk < 256; kk += 32) {
        __syncthreads();
        gld16(xh + (size_t)(m0 + r0) * Dd + k00 + kk + c0, &sAh[l0]);
        gld16(xh + (size_t)(m0 + r1) * Dd + k00 + kk + c0, &sAh[l1]);
        gld16(xl + (size_t)(m0 + r0) * Dd + k00 + kk + c0, &sAl[l0]);
        gld16(xl + (size_t)(m0 + r1) * Dd + k00 + kk + c0, &sAl[l1]);
        gld16(bsrc + k00 + kk, &sB[l0 & 2047]);
        __syncthreads();
#pragma unroll
        for (int mi = 0; mi < 2; mi++) {
            const int ar = wv * 32 + mi * 16 + lr;
            short8 ah = *(const short8*)&sAh[ar * 32 + quad * 8];
            short8 al = *(const short8*)&sAl[ar * 32 + quad * 8];
#pragma unroll
            for (int nj = 0; nj < 2; nj++) {
                short8 bh = *(const short8*)&sB[(nj * 16 + lr) * 32 + quad * 8];
                short8 bl = *(const short8*)&sB[1024 + (nj * 16 + lr) * 32 + quad * 8];
                acc[mi][nj] = __builtin_amdgcn_mfma_f32_16x16x32_bf16(ah, bh, acc[mi][nj], 0, 0, 0);
                acc[mi][nj] = __builtin_amdgcn_mfma_f32_16x16x32_bf16(ah, bl, acc[mi][nj], 0, 0, 0);
                acc[mi][nj] = __builtin_amdgcn_mfma_f32_16x16x32_bf16(al, bh, acc[mi][nj], 0, 0, 0);
            }
        }
    }
#pragma unroll
    for (int mi = 0; mi < 2; mi++)
#pragma unroll
        for (int r = 0; r < 4; r++) {
            const int t = m0 + wv * 32 + mi * 16 + quad * 4 + r;
#pragma unroll
            for (int nj = 0; nj < 2; nj++)
                part[((size_t)kb * Tt + t) * 32 + nj * 16 + lr] = acc[mi][nj][r];
        }
}

// ---------------- topk: reduce split-K partials, softmax, top4, shared gate ----------------
__global__ void topk_kernel(const float* __restrict__ part, float* __restrict__ comb,
                            int* __restrict__ selids, int* __restrict__ counts) {
    const int t = blockIdx.x * 64 + threadIdx.x;
    float lg[20];
#pragma unroll
    for (int j = 0; j < 20; j++) lg[j] = 0.f;
#pragma unroll
    for (int kb = 0; kb < 8; kb++) {
        const float* p = part + ((size_t)kb * Tt + t) * 32;
#pragma unroll
        for (int q = 0; q < 5; q++) {
            floatx4 a = *(const floatx4*)(p + q * 4);
            lg[q * 4 + 0] += a.x; lg[q * 4 + 1] += a.y;
            lg[q * 4 + 2] += a.z; lg[q * 4 + 3] += a.w;
        }
    }
    float mx = lg[0];
    for (int e = 1; e < Ee; e++) mx = fmaxf(mx, lg[e]);
    float p[Ee]; float sum = 0.f;
    for (int e = 0; e < Ee; e++) { p[e] = __expf(lg[e] - mx); sum += p[e]; }
    float inv = 1.f / sum;
    for (int e = 0; e < Ee; e++) p[e] *= inv;
    bool sel[Ee];
    for (int e = 0; e < Ee; e++) sel[e] = false;
    int ids[4];
    float ssum = 0.f;
    for (int k = 0; k < 4; k++) {
        int bi = 0; float bv = -1.f;
        for (int e = 0; e < Ee; e++)
            if (!sel[e] && p[e] > bv) { bv = p[e]; bi = e; }
        sel[bi] = true; ids[k] = bi; ssum += bv;
    }
    float rinv = 1.f / ssum;
    for (int e = 0; e < Ee; e++) comb[t * NE + e] = sel[e] ? p[e] * rinv : 0.f;
    comb[t * NE + Ee] = 1.f / (1.f + __expf(-lg[16]));
#pragma unroll
    for (int k = 0; k < 4; k++) {
        selids[t * 4 + k] = ids[k];
        atomicAdd(&counts[ids[k]], 1);
    }
}

// ---------------- offsets: tile-padded exclusive scan + block table ----------------
__global__ void offsets_kernel(const int* __restrict__ counts, int* __restrict__ off,
                               int* __restrict__ cursor, int* __restrict__ blocktab,
                               int* __restrict__ meta) {
    int acc = 0, nt = 0;
    for (int e = 0; e < NE; e++) {
        int c = (e < Ee) ? counts[e] : Tt;
        off[e] = acc;
        if (e < Ee) cursor[e] = 0;
        int tiles = (c + 127) >> 7;
        for (int tl = 0; tl < tiles; tl++) blocktab[nt++] = (e << 20) | (acc + tl * 128);
        acc += tiles << 7;
    }
    meta[0] = nt;
}

// ---------------- scatter: rowmap (pos -> token) + tokpos (token -> its 5 positions) ----------------
__global__ void scatter_kernel(const int* __restrict__ selids, const int* __restrict__ off,
                               int* __restrict__ cursor, int* __restrict__ rowmap,
                               int* __restrict__ tokpos) {
    int t = blockIdx.x * 256 + threadIdx.x;
    if (t >= Tt) return;
#pragma unroll
    for (int k = 0; k < 4; k++) {
        int e = selids[t * 4 + k];
        int r = atomicAdd(&cursor[e], 1);
        int pos = off[e] + r;
        rowmap[pos] = t;
        tokpos[t * 8 + k] = pos;
    }
    int sp = off[Ee] + t;
    rowmap[sp] = t;            // shared expert: identity
    tokpos[t * 8 + 4] = sp;
}

// ---------------- GEMM1: Hp[pos][f] = comb * silu(x@Wg_e) * (x@Wu_e) ----------------
// ROUND-9 VERIFIED VERSION (128x64 tile, 2-phase __syncthreads, swizzle, 76us).
// Round-10's 64-row m-split REGRESSED (87us): halving MFMA per K-step doubled the
// per-K-step barrier-drain events; the drain is a structural per-step tax that TLP
// does not remove. Reverted.
__global__ __launch_bounds__(256, 3) void gemm1_pre_kernel(
    const unsigned short* __restrict__ xb,
    const unsigned short* __restrict__ WguP,
    const float* __restrict__ comb,
    const int* __restrict__ rowmap,
    const int* __restrict__ blocktab,
    const int* __restrict__ meta,
    unsigned short* __restrict__ Hp)
{
    if ((int)blockIdx.y >= meta[0]) return;
    __shared__ unsigned short sAb[2][4096];   // A tiles (128x32)
    __shared__ unsigned short sGb[2][2048];   // gate B tiles (64x32)
    __shared__ unsigned short sUb[2][2048];   // up B tiles (64x32)
    const int info = blocktab[blockIdx.y];
    const int e  = info >> 20;
    const int m0 = info & 0xFFFFF;
    const int n0b = blockIdx.x;
    const int n0 = n0b * 64;
    const int tid = threadIdx.x;
    const int lane = tid & 63, wv = tid >> 6;
    const int wm = (wv >> 1) * 64, wn = (wv & 1) * 32;
    const int lr = lane & 15, quad = lane >> 4;
    const int swz8 = ((tid & 3) ^ ((tid >> 3) & 3)) * 8;
    const int koff = (quad ^ ((lr >> 1) & 3)) * 8;

    const unsigned short* wbase = WguP + (size_t)(e * 8 + n0b) * 64 * 4096;

    const int l0 = tid * 8;
    const int r0 = l0 >> 5;
    const int r1 = r0 + 64;
    const int tk0 = rowmap[m0 + r0];
    const int tk1 = rowmap[m0 + r1];
    const unsigned short* a0 = xb + (size_t)(tk0 < 0 ? 0 : tk0) * Dd + swz8;
    const unsigned short* a1 = xb + (size_t)(tk1 < 0 ? 0 : tk1) * Dd + swz8;

#define G1STAGE(B, KB) do { \
        const unsigned short* wsrc_ = wbase + (size_t)(KB) * 4096; \
        gld16(a0 + (KB) * 32, &sAb[B][l0]); \
        gld16(a1 + (KB) * 32, &sAb[B][l0 + 2048]); \
        gld16(wsrc_ + l0, &sGb[B][l0 & 2047]); \
        gld16(wsrc_ + 2048 + l0, &sUb[B][l0 & 2047]); \
    } while (0)

    floatx4 accg[4][2], accu[4][2];
#pragma unroll
    for (int i = 0; i < 4; i++)
#pragma unroll
        for (int j = 0; j < 2; j++) {
            accg[i][j] = (floatx4){0.f, 0.f, 0.f, 0.f};
            accu[i][j] = (floatx4){0.f, 0.f, 0.f, 0.f};
        }

    G1STAGE(0, 0);
    __syncthreads();                         // tile 0 resident
    for (int kb = 0; kb < 64; kb++) {
        const int cur = kb & 1;
        if (kb < 63) G1STAGE(cur ^ 1, kb + 1);   // in flight during MFMA below
        short8 af[4];
#pragma unroll
        for (int i = 0; i < 4; i++)
            af[i] = *(const short8*)&sAb[cur][(wm + i * 16 + lr) * 32 + koff];
#pragma unroll
        for (int j = 0; j < 2; j++) {
            short8 bg = *(const short8*)&sGb[cur][(wn + j * 16 + lr) * 32 + koff];
            short8 bu = *(const short8*)&sUb[cur][(wn + j * 16 + lr) * 32 + koff];
#pragma unroll
            for (int i = 0; i < 4; i++) {
                accg[i][j] = __builtin_amdgcn_mfma_f32_16x16x32_bf16(af[i], bg, accg[i][j], 0, 0, 0);
                accu[i][j] = __builtin_amdgcn_mfma_f32_16x16x32_bf16(af[i], bu, accu[i][j], 0, 0, 0);
            }
        }
        __syncthreads();                     // drains stage(kb+1); guards buffer reuse
    }
#undef G1STAGE
#pragma unroll
    for (int i = 0; i < 4; i++) {
#pragma unroll
        for (int r = 0; r < 4; r++) {
            const int pos = m0 + wm + i * 16 + quad * 4 + r;
            const int tok = rowmap[pos];
            const float wc = (tok >= 0) ? comb[tok * NE + e] : 0.f;
#pragma unroll
            for (int j = 0; j < 2; j++) {
                const float g = accg[i][j][r];
                const float u = accu[i][j][r];
                const float h = (g / (1.f + __expf(-g))) * u * wc;
                Hp[(size_t)pos * Ff + (n0 + wn + j * 16 + lr)] = f2bf(h);
            }
        }
    }
}

// ---------------- GEMM2: Op[pos] = Hp[pos] @ Wd_e (pre-cast bf16 Wd, packed bf16 out) ----------------
__global__ __launch_bounds__(256, 4) void gemm2_pre_kernel(
    const unsigned short* __restrict__ Hp,
    const unsigned short* __restrict__ WdP,
    const int* __restrict__ blocktab,
    const int* __restrict__ meta,
    unsigned short* __restrict__ Op)          // [MAXROWS][D] bf16 packed
{
    if ((int)blockIdx.y >= meta[0]) return;
    __shared__ unsigned short sA2[2][4096];
    __shared__ unsigned short sB2[2][4096];
    const int info = blocktab[blockIdx.y];
    const int e  = info >> 20;
    const int m0 = info & 0xFFFFF;
    const int n0b = blockIdx.x;
    const int n0 = n0b * 128;
    const int tid = threadIdx.x;
    const int lane = tid & 63, wv = tid >> 6;
    const int wm = (wv >> 1) * 64, wn = (wv & 1) * 64;
    const int lr = lane & 15, quad = lane >> 4;
    const int swz8 = ((tid & 3) ^ ((tid >> 3) & 3)) * 8;
    const int koff = (quad ^ ((lr >> 1) & 3)) * 8;

    const unsigned short* Ab = Hp + (size_t)m0 * Ff;
    const unsigned short* wbase = WdP + (size_t)(e * 16 + n0b) * 16 * 4096;

    const int l0 = tid * 8;
    const int r0 = l0 >> 5;
    const int r1 = r0 + 64;
    const unsigned short* aA0 = Ab + (size_t)r0 * Ff + swz8;
    const unsigned short* aA1 = Ab + (size_t)r1 * Ff + swz8;

#define G2STAGE(B, KB) do { \
        const unsigned short* wsrc_ = wbase + (size_t)(KB) * 4096; \
        gld16(aA0 + (KB) * 32, &sA2[B][l0]); \
        gld16(aA1 + (KB) * 32, &sA2[B][l0 + 2048]); \
        gld16(wsrc_ + l0, &sB2[B][l0]); \
        gld16(wsrc_ + 2048 + l0, &sB2[B][l0 + 2048]); \
    } while (0)

    floatx4 acc[4][4];
#pragma unroll
    for (int i = 0; i < 4; i++)
#pragma unroll
        for (int j = 0; j < 4; j++) acc[i][j] = (floatx4){0.f, 0.f, 0.f, 0.f};

    G2STAGE(0, 0);
    __syncthreads();
    for (int kb = 0; kb < 16; kb++) {
        const int cur = kb & 1;
        if (kb < 15) G2STAGE(cur ^ 1, kb + 1);
        short8 af[4];
#pragma unroll
        for (int i = 0; i < 4; i++)
            af[i] = *(const short8*)&sA2[cur][(wm + i * 16 + lr) * 32 + koff];
#pragma unroll
        for (int j = 0; j < 4; j++) {
            short8 bf = *(const short8*)&sB2[cur][(wn + j * 16 + lr) * 32 + koff];
#pragma unroll
            for (int i = 0; i < 4; i++)
                acc[i][j] = __builtin_amdgcn_mfma_f32_16x16x32_bf16(af[i], bf, acc[i][j], 0, 0, 0);
        }
        __syncthreads();                     // drains stage(kb+1); guards buffer reuse
    }
#undef G2STAGE
    // epilogue: per-wave 64x64 bf16 tile staged through LDS, coalesced ushort8 stores
    unsigned short* sOut = &sA2[0][0] + wv * 2048;  // 4 KB per wave
#pragma unroll
    for (int h = 0; h < 2; h++) {
#pragma unroll
        for (int ii = 0; ii < 2; ii++) {
            const int i = h * 2 + ii;
#pragma unroll
            for (int r = 0; r < 4; r++) {
                const int lrow = ii * 16 + quad * 4 + r;
#pragma unroll
                for (int j = 0; j < 4; j++)
                    sOut[lrow * 64 + j * 16 + lr] = f2bf(acc[i][j][r]);
            }
        }
        __syncthreads();
        const int prow0 = m0 + wm + h * 32;
#pragma unroll
        for (int it = 0; it < 4; it++) {
            const int idx = it * 512 + lane * 8;
            const int row = idx >> 6, col = idx & 63;
            ushort8v vv = *(const ushort8v*)&sOut[row * 64 + col];
            *(ushort8v*)&Op[(size_t)(prow0 + row) * Dd + n0 + wn + col] = vv;
        }
        __syncthreads();
    }
}

// ---------------- reduce: out[t] = sum of the token's 5 packed Op rows ----------------
__global__ __launch_bounds__(256) void reduce_kernel(
    const unsigned short* __restrict__ Op, const int* __restrict__ tokpos,
    float* __restrict__ out)
{
    const int t = blockIdx.x;
    const int c = threadIdx.x * 8;
    int ps[5];
#pragma unroll
    for (int k = 0; k < 5; k++) ps[k] = tokpos[t * 8 + k];
    float s[8];
#pragma unroll
    for (int j = 0; j < 8; j++) s[j] = 0.f;
#pragma unroll
    for (int k = 0; k < 5; k++) {
        ushort8v v = *(const ushort8v*)&Op[(size_t)ps[k] * Dd + c];
#pragma unroll
        for (int j = 0; j < 8; j++) s[j] += bf2f(v[j]);
    }
    *(floatx4*)(out + (size_t)t * Dd + c) = *(floatx4*)&s[0];
    *(floatx4*)(out + (size_t)t * Dd + c + 4) = *(floatx4*)&s[4];
}

extern "C" void kernel_launch(void* const* d_in, const int* in_sizes, int n_in,
                              void* d_out, int out_size, void* d_ws, size_t ws_size,
                              hipStream_t stream) {
    const float* x   = (const float*)d_in[0];
    const float* gw  = (const float*)d_in[1];
    const float* Wg  = (const float*)d_in[2];
    const float* Wu  = (const float*)d_in[3];
    const float* Wd  = (const float*)d_in[4];
    const float* sWg = (const float*)d_in[5];
    const float* sWu = (const float*)d_in[6];
    const float* sWd = (const float*)d_in[7];
    const float* sgw = (const float*)d_in[8];
    float* out = (float*)d_out;

    // workspace layout: 139.0 MB. WguP (dead after gemm1) overlays Op (live from gemm2).
    char* ws = (char*)d_ws;
    unsigned short* xb   = (unsigned short*)(ws);                //  8,388,608
    unsigned short* xl   = (unsigned short*)(ws + 8388608);      //  8,388,608
    unsigned short* Hp   = (unsigned short*)(ws + 16777216);     // 12,582,912
    float* part    = (float*)(ws + 29360128);                    //  2,097,152
    unsigned short* gB   = (unsigned short*)(ws + 31457280);     //    262,144
    float* comb    = (float*)(ws + 31719424);                    //    139,264
    int* selids    = (int*)(ws + 31858688);                      //     32,768
    int* counts    = (int*)(ws + 31891456);                      //         64
    int* off       = (int*)(ws + 31891520);                      //        128
    int* cursor    = (int*)(ws + 31891648);                      //         64
    int* meta      = (int*)(ws + 31891712);                      //         64
    int* blocktab  = (int*)(ws + 31891776);                      //        512
    int* rowmap    = (int*)(ws + 31892288);                      //     49,152
    int* tokpos    = (int*)(ws + 31941440);                      //     65,536
    unsigned short* WdP  = (unsigned short*)(ws + 32006976);     // 35,651,584
    unsigned short* WguP = (unsigned short*)(ws + 67658560);     // 71,303,168 (union w/ Op)
    unsigned short* Op   = (unsigned short*)(ws + 67658560);     // 50,331,648 (union w/ WguP)

    prep_kernel<<<PREP_BLOCKS, 256, 0, stream>>>(
        x, gw, sgw, Wg, sWg, Wu, sWu, Wd, sWd,
        xb, xl, gB, WguP, WdP, counts, rowmap);
    logits_kernel<<<dim3(Tt / 128, 8), 256, 0, stream>>>(xb, xl, gB, part);
    topk_kernel<<<Tt / 64, 64, 0, stream>>>(part, comb, selids, counts);
    offsets_kernel<<<1, 1, 0, stream>>>(counts, off, cursor, blocktab, meta);
    scatter_kernel<<<8, 256, 0, stream>>>(selids, off, cursor, rowmap, tokpos);
    gemm1_pre_kernel<<<dim3(Ff / 64, MAXTILES), 256, 0, stream>>>(
        xb, WguP, comb, rowmap, blocktab, meta, Hp);
    gemm2_pre_kernel<<<dim3(Dd / 128, MAXTILES), 256, 0, stream>>>(
        Hp, WdP, blocktab, meta, Op);
    reduce_kernel<<<Tt, 256, 0, stream>>>(Op, tokpos, out);
}